// Round 9
// baseline (247.207 us; speedup 1.0000x reference)
//
#include <hip/hip_runtime.h>
#include <hip/hip_bf16.h>

// DeepFM fused kernels for MI355X (gfx950).
// Pipeline per launch:
//   1. convert_w : W1,W2 fp32 -> bf16 in ws
//   2. fm_kernel : out[:,0] = fm_first + fm_second (fp32 exact)
//   3. gemm1     : H1 = relu(E @ W1^T + b1), E built on the fly in LDS (bf16 MFMA)
//   4. gemm2     : out[:,1:129] = relu(H1 @ W2^T + b2) (bf16 MFMA)

#define NROWS   65536
#define NFEAT   64
#define NDISC   62
#define DIM     16
#define K1      1024
#define H1N     256
#define H2N     128
#define OUTC    129

using f32x4  = __attribute__((ext_vector_type(4))) float;
using bf16x8 = __attribute__((ext_vector_type(8))) short;

__device__ __forceinline__ unsigned short f2bf(float f) {
    unsigned u = __builtin_bit_cast(unsigned, f);
    u = (u + 0x7FFFu + ((u >> 16) & 1u)) >> 16;   // RNE
    return (unsigned short)u;
}

__device__ __forceinline__ void async16(const void* g, void* l) {
    __builtin_amdgcn_global_load_lds(
        (const __attribute__((address_space(1))) void*)g,
        (__attribute__((address_space(3))) void*)l, 16, 0, 0);
}

// ---------------------------------------------------------------- convert_w
__global__ __launch_bounds__(256) void convert_w(const float* __restrict__ W1,
                                                 const float* __restrict__ W2,
                                                 unsigned short* __restrict__ W1b,
                                                 unsigned short* __restrict__ W2b) {
    int i = blockIdx.x * 256 + threadIdx.x;
    if (i < H1N * K1) W1b[i] = f2bf(W1[i]);
    if (i < H2N * H1N) W2b[i] = f2bf(W2[i]);
}

// ---------------------------------------------------------------- fm_kernel
// one wave per row; 8 rows per wave via loop; grid = NROWS/32 blocks of 256
__global__ __launch_bounds__(256) void fm_kernel(const float* __restrict__ x,
                                                 const float* __restrict__ tbl,
                                                 const float* __restrict__ Wc,
                                                 const float* __restrict__ bc,
                                                 const float* __restrict__ Wf,
                                                 const float* __restrict__ bfp,
                                                 float* __restrict__ out) {
    __shared__ float tblL[NDISC * 2 * DIM];
    __shared__ float WcL[32 * 2];
    __shared__ float bcL[32];
    __shared__ float WfL[64];
    const int t = threadIdx.x, l = t & 63, w = t >> 6;
    for (int i = t; i < NDISC * 2 * DIM; i += 256) tblL[i] = tbl[i];
    if (t < 64) WcL[t] = Wc[t];
    if (t >= 64 && t < 96) bcL[t - 64] = bc[t - 64];
    if (t >= 96 && t < 160) WfL[t - 96] = Wf[t - 96];
    __syncthreads();
    const float bf0 = bfp[0];

    for (int it = 0; it < 8; ++it) {
        const int row = blockIdx.x * 32 + w * 8 + it;
        const float xv = x[(size_t)row * NFEAT + l];
        const float c0 = __shfl(xv, 62);
        const float c1 = __shfl(xv, 63);
        float e[16];
        if (l < NDISC) {
            const int bit = ((int)xv) & 1;
            const float* tv = &tblL[(l * 2 + bit) * DIM];
            #pragma unroll
            for (int d = 0; d < 16; ++d) e[d] = tv[d];
        } else {
            const int j0 = (l - NDISC) * 16;
            #pragma unroll
            for (int d = 0; d < 16; ++d) {
                const int j = j0 + d;
                e[d] = bcL[j] + c0 * WcL[2 * j] + c1 * WcL[2 * j + 1];
            }
        }
        float ssq = 0.f, f1 = xv * WfL[l];
        #pragma unroll
        for (int d = 0; d < 16; ++d) ssq += e[d] * e[d];
        #pragma unroll
        for (int d = 0; d < 16; ++d) {
            float s = e[d];
            s += __shfl_xor(s, 1);  s += __shfl_xor(s, 2);  s += __shfl_xor(s, 4);
            s += __shfl_xor(s, 8);  s += __shfl_xor(s, 16); s += __shfl_xor(s, 32);
            e[d] = s;
        }
        ssq += __shfl_xor(ssq, 1); ssq += __shfl_xor(ssq, 2); ssq += __shfl_xor(ssq, 4);
        ssq += __shfl_xor(ssq, 8); ssq += __shfl_xor(ssq, 16); ssq += __shfl_xor(ssq, 32);
        f1 += __shfl_xor(f1, 1);   f1 += __shfl_xor(f1, 2);   f1 += __shfl_xor(f1, 4);
        f1 += __shfl_xor(f1, 8);   f1 += __shfl_xor(f1, 16);  f1 += __shfl_xor(f1, 32);
        if (l == 0) {
            float s2 = 0.f;
            #pragma unroll
            for (int d = 0; d < 16; ++d) s2 += e[d] * e[d];
            out[(size_t)row * OUTC] = f1 + bf0 + 0.5f * (s2 - ssq);
        }
    }
}

// ---------------------------------------------------------------- gemm1
// block = 512 thr (8 waves, 2x4), tile 128(M) x 256(N=all H1), BK=64 (4 feats)
// A-tile (E) built on the fly from x bits + emb tables; B-tile = W1b via
// global_load_lds dwordx4.
__global__ __launch_bounds__(512, 4) void gemm1_fused(
        const float* __restrict__ x,
        const float* __restrict__ tbl,
        const float* __restrict__ Wc,
        const float* __restrict__ bc,
        const unsigned short* __restrict__ W1b,
        const float* __restrict__ b1,
        unsigned short* __restrict__ H1b) {
    __shared__ unsigned short ldsA[128 * 64];   // E tile, row-major K-contig
    __shared__ unsigned short ldsB[256 * 64];   // W1 tile, row-major K-contig
    __shared__ unsigned char  xb[128 * 64];
    __shared__ float contf[128 * 2];
    __shared__ float tblL[NDISC * 2 * DIM];
    __shared__ float WcL[64];
    __shared__ float bcL[32];

    const int t  = threadIdx.x;
    const int l  = t & 63;
    const int w  = t >> 6;        // 0..7
    const int wr = w >> 2;        // 0..1  (64-row band)
    const int wc = w & 3;         // 0..3  (64-col band)
    const int m0 = blockIdx.x * 128;

    for (int i = t; i < NDISC * 2 * DIM; i += 512) tblL[i] = tbl[i];
    if (t < 64) WcL[t] = Wc[t];
    if (t >= 64 && t < 96) bcL[t - 64] = bc[t - 64];

    // stage x tile: thread t -> row t>>2, 16 cols at (t&3)*16, pack bits to bytes
    {
        const int row = t >> 2, cbase = (t & 3) * 16;
        const float4* xp = (const float4*)(x + (size_t)(m0 + row) * NFEAT + cbase);
        #pragma unroll
        for (int q = 0; q < 4; ++q) {
            float4 v = xp[q];
            unsigned pk = ((unsigned)(int)v.x) | ((unsigned)(int)v.y << 8) |
                          ((unsigned)(int)v.z << 16) | ((unsigned)(int)v.w << 24);
            *(unsigned*)&xb[row * 64 + cbase + q * 4] = pk;
            if (cbase + q * 4 == 60) {          // cols 62,63 are the cont values
                contf[row * 2]     = v.z;
                contf[row * 2 + 1] = v.w;
            }
        }
    }
    __syncthreads();

    f32x4 acc[4][4] = {};

    for (int ks = 0; ks < 16; ++ks) {
        const int k0 = ks * 64;
        const int f0 = ks * 4;

        // build A tile: 1024 chunks of 8 bf16; thread does chunks t and t+512
        #pragma unroll
        for (int p = 0; p < 2; ++p) {
            const int chunk = p * 512 + t;
            const int row = chunk >> 3;
            const int cc  = chunk & 7;
            const int fl  = cc >> 1;
            const int d0  = (cc & 1) * 8;
            const int f   = f0 + fl;
            float vals[8];
            if (f < NDISC) {
                const int bit = xb[row * 64 + f] & 1;
                const float* tv = &tblL[(f * 2 + bit) * DIM + d0];
                #pragma unroll
                for (int d = 0; d < 8; ++d) vals[d] = tv[d];
            } else {
                const float c0v = contf[row * 2], c1v = contf[row * 2 + 1];
                const int j0 = (f - NDISC) * 16 + d0;
                #pragma unroll
                for (int d = 0; d < 8; ++d) {
                    const int j = j0 + d;
                    vals[d] = bcL[j] + c0v * WcL[2 * j] + c1v * WcL[2 * j + 1];
                }
            }
            bf16x8 pk;
            #pragma unroll
            for (int d = 0; d < 8; ++d) pk[d] = (short)f2bf(vals[d]);
            *(bf16x8*)&ldsA[chunk * 8] = pk;
        }

        // stage B tile (W1): 2048 chunks of 16B, 4 per thread, linear LDS
        // 512 thr * 16B = 8192 B = 4096 shorts per p-step
        {
            unsigned short* dstbase = &ldsB[0] + w * 512;   // wave-uniform (w*1024 B)
            #pragma unroll
            for (int p = 0; p < 4; ++p) {
                const int chunk = p * 512 + t;
                const int row = chunk >> 3;
                const int cc  = chunk & 7;
                async16(W1b + (size_t)row * K1 + k0 + cc * 8, dstbase + p * 4096);
            }
        }
        __syncthreads();

        #pragma unroll
        for (int sub = 0; sub < 2; ++sub) {
            bf16x8 af[4], bfr[4];
            #pragma unroll
            for (int i = 0; i < 4; ++i)
                af[i] = *(const bf16x8*)&ldsA[(wr * 64 + i * 16 + (l & 15)) * 64 + sub * 32 + (l >> 4) * 8];
            #pragma unroll
            for (int j = 0; j < 4; ++j)
                bfr[j] = *(const bf16x8*)&ldsB[(wc * 64 + j * 16 + (l & 15)) * 64 + sub * 32 + (l >> 4) * 8];
            #pragma unroll
            for (int i = 0; i < 4; ++i)
                #pragma unroll
                for (int j = 0; j < 4; ++j)
                    acc[i][j] = __builtin_amdgcn_mfma_f32_16x16x32_bf16(af[i], bfr[j], acc[i][j], 0, 0, 0);
        }
        __syncthreads();
    }

    // epilogue: relu(+b1) -> H1 bf16
    #pragma unroll
    for (int i = 0; i < 4; ++i) {
        const int rbase = m0 + wr * 64 + i * 16 + (l >> 4) * 4;
        #pragma unroll
        for (int j = 0; j < 4; ++j) {
            const int col = wc * 64 + j * 16 + (l & 15);
            const float bias = b1[col];
            #pragma unroll
            for (int r = 0; r < 4; ++r) {
                float v = acc[i][j][r] + bias;
                v = v > 0.f ? v : 0.f;
                H1b[(size_t)(rbase + r) * H1N + col] = f2bf(v);
            }
        }
    }
}

// ---------------------------------------------------------------- gemm2
// block = 256 thr (4 waves, 2x2), tile 128x128, BK=128 (2 k-steps), K=256
// 256 thr * 16B = 4096 B = 2048 shorts per p-step
__global__ __launch_bounds__(256, 2) void gemm2_k(
        const unsigned short* __restrict__ H1b,
        const unsigned short* __restrict__ W2b,
        const float* __restrict__ b2,
        float* __restrict__ out) {
    __shared__ unsigned short ldsA[128 * 128];
    __shared__ unsigned short ldsB[128 * 128];
    const int t = threadIdx.x, l = t & 63, w = t >> 6;
    const int wr = w >> 1, wc = w & 1;
    const int m0 = blockIdx.x * 128;

    f32x4 acc[4][4] = {};

    for (int ks = 0; ks < 2; ++ks) {
        const int k0 = ks * 128;
        {
            unsigned short* da = &ldsA[0] + w * 512;   // w*1024 B, wave-uniform
            unsigned short* db = &ldsB[0] + w * 512;
            #pragma unroll
            for (int p = 0; p < 8; ++p) {
                const int chunk = p * 256 + t;
                const int row = chunk >> 4;
                const int cc  = chunk & 15;
                async16(H1b + (size_t)(m0 + row) * H1N + k0 + cc * 8, da + p * 2048);
            }
            #pragma unroll
            for (int p = 0; p < 8; ++p) {
                const int chunk = p * 256 + t;
                const int row = chunk >> 4;
                const int cc  = chunk & 15;
                async16(W2b + (size_t)row * H1N + k0 + cc * 8, db + p * 2048);
            }
        }
        __syncthreads();
        #pragma unroll
        for (int sub = 0; sub < 4; ++sub) {
            bf16x8 af[4], bfr[4];
            #pragma unroll
            for (int i = 0; i < 4; ++i)
                af[i] = *(const bf16x8*)&ldsA[(wr * 64 + i * 16 + (l & 15)) * 128 + sub * 32 + (l >> 4) * 8];
            #pragma unroll
            for (int j = 0; j < 4; ++j)
                bfr[j] = *(const bf16x8*)&ldsB[(wc * 64 + j * 16 + (l & 15)) * 128 + sub * 32 + (l >> 4) * 8];
            #pragma unroll
            for (int i = 0; i < 4; ++i)
                #pragma unroll
                for (int j = 0; j < 4; ++j)
                    acc[i][j] = __builtin_amdgcn_mfma_f32_16x16x32_bf16(af[i], bfr[j], acc[i][j], 0, 0, 0);
        }
        __syncthreads();
    }

    // epilogue: out[:, 1 + n] = relu(acc + b2[n])
    #pragma unroll
    for (int i = 0; i < 4; ++i) {
        const int rbase = m0 + wr * 64 + i * 16 + (l >> 4) * 4;
        #pragma unroll
        for (int j = 0; j < 4; ++j) {
            const int n = wc * 64 + j * 16 + (l & 15);
            const float bias = b2[n];
            #pragma unroll
            for (int r = 0; r < 4; ++r) {
                float v = acc[i][j][r] + bias;
                v = v > 0.f ? v : 0.f;
                out[(size_t)(rbase + r) * OUTC + 1 + n] = v;
            }
        }
    }
}

// ---------------------------------------------------------------- launch
extern "C" void kernel_launch(void* const* d_in, const int* in_sizes, int n_in,
                              void* d_out, int out_size, void* d_ws, size_t ws_size,
                              hipStream_t stream) {
    const float* x   = (const float*)d_in[0];
    const float* tbl = (const float*)d_in[1];
    const float* Wc  = (const float*)d_in[2];
    const float* bc  = (const float*)d_in[3];
    const float* Wf  = (const float*)d_in[4];
    const float* bfp = (const float*)d_in[5];
    const float* W1  = (const float*)d_in[6];
    const float* b1  = (const float*)d_in[7];
    const float* W2  = (const float*)d_in[8];
    const float* b2  = (const float*)d_in[9];
    float* out = (float*)d_out;

    char* ws = (char*)d_ws;
    unsigned short* W1b = (unsigned short*)ws;                  // 512 KiB
    unsigned short* W2b = (unsigned short*)(ws + 524288);       // 64 KiB
    unsigned short* H1b = (unsigned short*)(ws + 589824);       // 32 MiB

    convert_w<<<dim3(H1N * K1 / 256), dim3(256), 0, stream>>>(W1, W2, W1b, W2b);
    fm_kernel<<<dim3(NROWS / 32), dim3(256), 0, stream>>>(x, tbl, Wc, bc, Wf, bfp, out);
    gemm1_fused<<<dim3(NROWS / 128), dim3(512), 0, stream>>>(x, tbl, Wc, bc, W1b, b1, H1b);
    gemm2_k<<<dim3(NROWS / 128), dim3(256), 0, stream>>>(H1b, W2b, b2, out);
}

// Round 10
// 166.652 us; speedup vs baseline: 1.4834x; 1.4834x over previous
//
#include <hip/hip_runtime.h>
#include <hip/hip_bf16.h>

// DeepFM fused kernels for MI355X (gfx950).
// Pipeline per launch:
//   1. convert_w : W1,W2 fp32 -> bf16 in ws
//   2. fm_kernel : out[:,0] = fm_first + fm_second (fp32, lane-local reduction)
//   3. gemm1     : H1 = relu(E @ W1^T + b1), E built on the fly in LDS (bf16 MFMA)
//   4. gemm2     : out[:,1:129] = relu(H1 @ W2^T + b2) (bf16 MFMA)

#define NROWS   65536
#define NFEAT   64
#define NDISC   62
#define DIM     16
#define K1      1024
#define H1N     256
#define H2N     128
#define OUTC    129

using f32x4  = __attribute__((ext_vector_type(4))) float;
using bf16x8 = __attribute__((ext_vector_type(8))) short;

__device__ __forceinline__ unsigned short f2bf(float f) {
    unsigned u = __builtin_bit_cast(unsigned, f);
    u = (u + 0x7FFFu + ((u >> 16) & 1u)) >> 16;   // RNE
    return (unsigned short)u;
}

__device__ __forceinline__ void async16(const void* g, void* l) {
    __builtin_amdgcn_global_load_lds(
        (const __attribute__((address_space(1))) void*)g,
        (__attribute__((address_space(3))) void*)l, 16, 0, 0);
}

// ---------------------------------------------------------------- convert_w
__global__ __launch_bounds__(256) void convert_w(const float* __restrict__ W1,
                                                 const float* __restrict__ W2,
                                                 unsigned short* __restrict__ W1b,
                                                 unsigned short* __restrict__ W2b) {
    int i = blockIdx.x * 256 + threadIdx.x;
    if (i < H1N * K1) W1b[i] = f2bf(W1[i]);
    if (i < H2N * H1N) W2b[i] = f2bf(W2[i]);
}

// ---------------------------------------------------------------- fm_kernel
// wave = 4 rows x 16 dims; reduction over features is lane-local (registers).
// Per 4-row group: ~16 shuffles total vs ~870 in the old per-row-per-dim
// shuffle-reduce version (which measured 100us, 4.6M LDS bank conflicts).
__global__ __launch_bounds__(256) void fm_kernel(const float* __restrict__ x,
                                                 const float* __restrict__ tbl,
                                                 const float* __restrict__ Wc,
                                                 const float* __restrict__ bc,
                                                 const float* __restrict__ Wf,
                                                 const float* __restrict__ bfp,
                                                 float* __restrict__ out) {
    __shared__ float tblL[NDISC * 2 * DIM];
    __shared__ float WcL[64];
    __shared__ float bcL[32];
    __shared__ float WfL[64];
    const int t = threadIdx.x, l = t & 63, w = t >> 6;
    const int d = l & 15;
    for (int i = t; i < NDISC * 2 * DIM; i += 256) tblL[i] = tbl[i];
    if (t < 64) WcL[t] = Wc[t];
    else if (t < 96) bcL[t - 64] = bc[t - 64];
    else if (t < 160) WfL[t - 96] = Wf[t - 96];
    __syncthreads();
    const float bf0 = bfp[0];

    const int waveId = blockIdx.x * 4 + w;          // 0..8191 (2048 blocks)
    #pragma unroll
    for (int it = 0; it < 2; ++it) {
        const int grp = waveId + it * 8192;         // 0..16383
        const int row = grp * 4 + (l >> 4);
        const float4 v = *(const float4*)(x + (size_t)row * NFEAT + d * 4);

        // assemble 62-bit discrete mask across the 16-lane group
        unsigned long long m =
            ((unsigned long long)((int)v.x & 1)) |
            ((unsigned long long)((int)v.y & 1) << 1) |
            ((unsigned long long)((int)v.z & 1) << 2) |
            ((unsigned long long)((int)v.w & 1) << 3);
        m <<= (d * 4);
        m |= __shfl_xor(m, 1); m |= __shfl_xor(m, 2);
        m |= __shfl_xor(m, 4); m |= __shfl_xor(m, 8);
        const float c0 = __shfl(v.z, l | 15);       // x[row][62]
        const float c1 = __shfl(v.w, l | 15);       // x[row][63]

        // fm_first partial: this lane covers features 4d..4d+3
        float fp = v.x * WfL[4 * d] + v.y * WfL[4 * d + 1] +
                   v.z * WfL[4 * d + 2] + v.w * WfL[4 * d + 3];

        // lane-local accumulation over the 62 discrete features
        float se = 0.f, ssq = 0.f;
        #pragma unroll
        for (int f = 0; f < NDISC; ++f) {
            const int bit = (int)((m >> f) & 1ULL);
            const float e = tblL[(f * 2 + bit) * DIM + d];
            se += e; ssq += e * e;
        }
        // cont features 62,63: e[62+j][d] = bc[j*16+d] + c0*Wc[.,0] + c1*Wc[.,1]
        {
            const float e62 = bcL[d]      + c0 * WcL[2 * d]            + c1 * WcL[2 * d + 1];
            const float e63 = bcL[16 + d] + c0 * WcL[2 * (16 + d)]     + c1 * WcL[2 * (16 + d) + 1];
            se += e62 + e63; ssq += e62 * e62 + e63 * e63;
        }

        // fm_second = 0.5*(sum_d se^2 - sum_d ssq); reduce over the 16 lanes
        float u = se * se - ssq;
        u  += __shfl_xor(u, 1);  u  += __shfl_xor(u, 2);
        u  += __shfl_xor(u, 4);  u  += __shfl_xor(u, 8);
        fp += __shfl_xor(fp, 1); fp += __shfl_xor(fp, 2);
        fp += __shfl_xor(fp, 4); fp += __shfl_xor(fp, 8);
        if (d == 0) out[(size_t)row * OUTC] = fp + bf0 + 0.5f * u;
    }
}

// ---------------------------------------------------------------- gemm1
// block = 512 thr (8 waves, 2x4), tile 128(M) x 256(N=all H1), BK=64 (4 feats)
// A-tile (E) built on the fly from x bits + emb tables; B-tile = W1b via
// global_load_lds dwordx4.
__global__ __launch_bounds__(512, 4) void gemm1_fused(
        const float* __restrict__ x,
        const float* __restrict__ tbl,
        const float* __restrict__ Wc,
        const float* __restrict__ bc,
        const unsigned short* __restrict__ W1b,
        const float* __restrict__ b1,
        unsigned short* __restrict__ H1b) {
    __shared__ unsigned short ldsA[128 * 64];   // E tile, row-major K-contig
    __shared__ unsigned short ldsB[256 * 64];   // W1 tile, row-major K-contig
    __shared__ unsigned char  xb[128 * 64];
    __shared__ float contf[128 * 2];
    __shared__ float tblL[NDISC * 2 * DIM];
    __shared__ float WcL[64];
    __shared__ float bcL[32];

    const int t  = threadIdx.x;
    const int l  = t & 63;
    const int w  = t >> 6;        // 0..7
    const int wr = w >> 2;        // 0..1  (64-row band)
    const int wc = w & 3;         // 0..3  (64-col band)
    const int m0 = blockIdx.x * 128;

    for (int i = t; i < NDISC * 2 * DIM; i += 512) tblL[i] = tbl[i];
    if (t < 64) WcL[t] = Wc[t];
    if (t >= 64 && t < 96) bcL[t - 64] = bc[t - 64];

    // stage x tile: thread t -> row t>>2, 16 cols at (t&3)*16, pack bits to bytes
    {
        const int row = t >> 2, cbase = (t & 3) * 16;
        const float4* xp = (const float4*)(x + (size_t)(m0 + row) * NFEAT + cbase);
        #pragma unroll
        for (int q = 0; q < 4; ++q) {
            float4 v = xp[q];
            unsigned pk = ((unsigned)(int)v.x) | ((unsigned)(int)v.y << 8) |
                          ((unsigned)(int)v.z << 16) | ((unsigned)(int)v.w << 24);
            *(unsigned*)&xb[row * 64 + cbase + q * 4] = pk;
            if (cbase + q * 4 == 60) {          // cols 62,63 are the cont values
                contf[row * 2]     = v.z;
                contf[row * 2 + 1] = v.w;
            }
        }
    }
    __syncthreads();

    f32x4 acc[4][4] = {};

    for (int ks = 0; ks < 16; ++ks) {
        const int k0 = ks * 64;
        const int f0 = ks * 4;

        // build A tile: 1024 chunks of 8 bf16; thread does chunks t and t+512
        #pragma unroll
        for (int p = 0; p < 2; ++p) {
            const int chunk = p * 512 + t;
            const int row = chunk >> 3;
            const int cc  = chunk & 7;
            const int fl  = cc >> 1;
            const int d0  = (cc & 1) * 8;
            const int f   = f0 + fl;
            float vals[8];
            if (f < NDISC) {
                const int bit = xb[row * 64 + f] & 1;
                const float* tv = &tblL[(f * 2 + bit) * DIM + d0];
                #pragma unroll
                for (int d = 0; d < 8; ++d) vals[d] = tv[d];
            } else {
                const float c0v = contf[row * 2], c1v = contf[row * 2 + 1];
                const int j0 = (f - NDISC) * 16 + d0;
                #pragma unroll
                for (int d = 0; d < 8; ++d) {
                    const int j = j0 + d;
                    vals[d] = bcL[j] + c0v * WcL[2 * j] + c1v * WcL[2 * j + 1];
                }
            }
            bf16x8 pk;
            #pragma unroll
            for (int d = 0; d < 8; ++d) pk[d] = (short)f2bf(vals[d]);
            *(bf16x8*)&ldsA[chunk * 8] = pk;
        }

        // stage B tile (W1): 2048 chunks of 16B, 4 per thread, linear LDS
        // 512 thr * 16B = 8192 B = 4096 shorts per p-step
        {
            unsigned short* dstbase = &ldsB[0] + w * 512;   // wave-uniform (w*1024 B)
            #pragma unroll
            for (int p = 0; p < 4; ++p) {
                const int chunk = p * 512 + t;
                const int row = chunk >> 3;
                const int cc  = chunk & 7;
                async16(W1b + (size_t)row * K1 + k0 + cc * 8, dstbase + p * 4096);
            }
        }
        __syncthreads();

        #pragma unroll
        for (int sub = 0; sub < 2; ++sub) {
            bf16x8 af[4], bfr[4];
            #pragma unroll
            for (int i = 0; i < 4; ++i)
                af[i] = *(const bf16x8*)&ldsA[(wr * 64 + i * 16 + (l & 15)) * 64 + sub * 32 + (l >> 4) * 8];
            #pragma unroll
            for (int j = 0; j < 4; ++j)
                bfr[j] = *(const bf16x8*)&ldsB[(wc * 64 + j * 16 + (l & 15)) * 64 + sub * 32 + (l >> 4) * 8];
            #pragma unroll
            for (int i = 0; i < 4; ++i)
                #pragma unroll
                for (int j = 0; j < 4; ++j)
                    acc[i][j] = __builtin_amdgcn_mfma_f32_16x16x32_bf16(af[i], bfr[j], acc[i][j], 0, 0, 0);
        }
        __syncthreads();
    }

    // epilogue: relu(+b1) -> H1 bf16
    #pragma unroll
    for (int i = 0; i < 4; ++i) {
        const int rbase = m0 + wr * 64 + i * 16 + (l >> 4) * 4;
        #pragma unroll
        for (int j = 0; j < 4; ++j) {
            const int col = wc * 64 + j * 16 + (l & 15);
            const float bias = b1[col];
            #pragma unroll
            for (int r = 0; r < 4; ++r) {
                float v = acc[i][j][r] + bias;
                v = v > 0.f ? v : 0.f;
                H1b[(size_t)(rbase + r) * H1N + col] = f2bf(v);
            }
        }
    }
}

// ---------------------------------------------------------------- gemm2
// block = 256 thr (4 waves, 2x2), tile 128x128, BK=128 (2 k-steps), K=256
// 256 thr * 16B = 4096 B = 2048 shorts per p-step
__global__ __launch_bounds__(256, 2) void gemm2_k(
        const unsigned short* __restrict__ H1b,
        const unsigned short* __restrict__ W2b,
        const float* __restrict__ b2,
        float* __restrict__ out) {
    __shared__ unsigned short ldsA[128 * 128];
    __shared__ unsigned short ldsB[128 * 128];
    const int t = threadIdx.x, l = t & 63, w = t >> 6;
    const int wr = w >> 1, wc = w & 1;
    const int m0 = blockIdx.x * 128;

    f32x4 acc[4][4] = {};

    for (int ks = 0; ks < 2; ++ks) {
        const int k0 = ks * 128;
        {
            unsigned short* da = &ldsA[0] + w * 512;   // w*1024 B, wave-uniform
            unsigned short* db = &ldsB[0] + w * 512;
            #pragma unroll
            for (int p = 0; p < 8; ++p) {
                const int chunk = p * 256 + t;
                const int row = chunk >> 4;
                const int cc  = chunk & 15;
                async16(H1b + (size_t)(m0 + row) * H1N + k0 + cc * 8, da + p * 2048);
            }
            #pragma unroll
            for (int p = 0; p < 8; ++p) {
                const int chunk = p * 256 + t;
                const int row = chunk >> 4;
                const int cc  = chunk & 15;
                async16(W2b + (size_t)row * H1N + k0 + cc * 8, db + p * 2048);
            }
        }
        __syncthreads();
        #pragma unroll
        for (int sub = 0; sub < 4; ++sub) {
            bf16x8 af[4], bfr[4];
            #pragma unroll
            for (int i = 0; i < 4; ++i)
                af[i] = *(const bf16x8*)&ldsA[(wr * 64 + i * 16 + (l & 15)) * 128 + sub * 32 + (l >> 4) * 8];
            #pragma unroll
            for (int j = 0; j < 4; ++j)
                bfr[j] = *(const bf16x8*)&ldsB[(wc * 64 + j * 16 + (l & 15)) * 128 + sub * 32 + (l >> 4) * 8];
            #pragma unroll
            for (int i = 0; i < 4; ++i)
                #pragma unroll
                for (int j = 0; j < 4; ++j)
                    acc[i][j] = __builtin_amdgcn_mfma_f32_16x16x32_bf16(af[i], bfr[j], acc[i][j], 0, 0, 0);
        }
        __syncthreads();
    }

    // epilogue: out[:, 1 + n] = relu(acc + b2[n])
    #pragma unroll
    for (int i = 0; i < 4; ++i) {
        const int rbase = m0 + wr * 64 + i * 16 + (l >> 4) * 4;
        #pragma unroll
        for (int j = 0; j < 4; ++j) {
            const int n = wc * 64 + j * 16 + (l & 15);
            const float bias = b2[n];
            #pragma unroll
            for (int r = 0; r < 4; ++r) {
                float v = acc[i][j][r] + bias;
                v = v > 0.f ? v : 0.f;
                out[(size_t)(rbase + r) * OUTC + 1 + n] = v;
            }
        }
    }
}

// ---------------------------------------------------------------- launch
extern "C" void kernel_launch(void* const* d_in, const int* in_sizes, int n_in,
                              void* d_out, int out_size, void* d_ws, size_t ws_size,
                              hipStream_t stream) {
    const float* x   = (const float*)d_in[0];
    const float* tbl = (const float*)d_in[1];
    const float* Wc  = (const float*)d_in[2];
    const float* bc  = (const float*)d_in[3];
    const float* Wf  = (const float*)d_in[4];
    const float* bfp = (const float*)d_in[5];
    const float* W1  = (const float*)d_in[6];
    const float* b1  = (const float*)d_in[7];
    const float* W2  = (const float*)d_in[8];
    const float* b2  = (const float*)d_in[9];
    float* out = (float*)d_out;

    char* ws = (char*)d_ws;
    unsigned short* W1b = (unsigned short*)ws;                  // 512 KiB
    unsigned short* W2b = (unsigned short*)(ws + 524288);       // 64 KiB
    unsigned short* H1b = (unsigned short*)(ws + 589824);       // 32 MiB

    convert_w<<<dim3(H1N * K1 / 256), dim3(256), 0, stream>>>(W1, W2, W1b, W2b);
    fm_kernel<<<dim3(2048), dim3(256), 0, stream>>>(x, tbl, Wc, bc, Wf, bfp, out);
    gemm1_fused<<<dim3(NROWS / 128), dim3(512), 0, stream>>>(x, tbl, Wc, bc, W1b, b1, H1b);
    gemm2_k<<<dim3(NROWS / 128), dim3(256), 0, stream>>>(H1b, W2b, b2, out);
}

// Round 11
// 146.346 us; speedup vs baseline: 1.6892x; 1.1388x over previous
//
#include <hip/hip_runtime.h>
#include <hip/hip_bf16.h>

// DeepFM fused kernels for MI355X (gfx950).
// Pipeline per launch:
//   1. convert_w : W1,W2 fp32 -> bf16 in ws
//   2. fm_kernel : out[:,0] = fm_first + fm_second (fp32, lane-local reduction)
//   3. gemm1     : H1 = relu(E @ W1^T + b1), E built on the fly in LDS (bf16 MFMA)
//   4. gemm2     : out[:,1:129] = relu(H1 @ W2^T + b2) (bf16 MFMA)
// R10: XOR-swizzle (slot ^= row&7) on all GEMM LDS tiles (rule #21: swizzled
//      global source + linear gload_lds dest + swizzled read); bf16 emb table
//      in gemm1 (removes f2bf VALU chain from A-build, bit-identical).

#define NROWS   65536
#define NFEAT   64
#define NDISC   62
#define DIM     16
#define K1      1024
#define H1N     256
#define H2N     128
#define OUTC    129

using f32x4  = __attribute__((ext_vector_type(4))) float;
using bf16x8 = __attribute__((ext_vector_type(8))) short;

__device__ __forceinline__ unsigned short f2bf(float f) {
    unsigned u = __builtin_bit_cast(unsigned, f);
    u = (u + 0x7FFFu + ((u >> 16) & 1u)) >> 16;   // RNE
    return (unsigned short)u;
}

__device__ __forceinline__ void async16(const void* g, void* l) {
    __builtin_amdgcn_global_load_lds(
        (const __attribute__((address_space(1))) void*)g,
        (__attribute__((address_space(3))) void*)l, 16, 0, 0);
}

// ---------------------------------------------------------------- convert_w
__global__ __launch_bounds__(256) void convert_w(const float* __restrict__ W1,
                                                 const float* __restrict__ W2,
                                                 unsigned short* __restrict__ W1b,
                                                 unsigned short* __restrict__ W2b) {
    int i = blockIdx.x * 256 + threadIdx.x;
    if (i < H1N * K1) W1b[i] = f2bf(W1[i]);
    if (i < H2N * H1N) W2b[i] = f2bf(W2[i]);
}

// ---------------------------------------------------------------- fm_kernel
// wave = 4 rows x 16 dims; reduction over features is lane-local (registers).
__global__ __launch_bounds__(256) void fm_kernel(const float* __restrict__ x,
                                                 const float* __restrict__ tbl,
                                                 const float* __restrict__ Wc,
                                                 const float* __restrict__ bc,
                                                 const float* __restrict__ Wf,
                                                 const float* __restrict__ bfp,
                                                 float* __restrict__ out) {
    __shared__ float tblL[NDISC * 2 * DIM];
    __shared__ float WcL[64];
    __shared__ float bcL[32];
    __shared__ float WfL[64];
    const int t = threadIdx.x, l = t & 63, w = t >> 6;
    const int d = l & 15;
    for (int i = t; i < NDISC * 2 * DIM; i += 256) tblL[i] = tbl[i];
    if (t < 64) WcL[t] = Wc[t];
    else if (t < 96) bcL[t - 64] = bc[t - 64];
    else if (t < 160) WfL[t - 96] = Wf[t - 96];
    __syncthreads();
    const float bf0 = bfp[0];

    const int waveId = blockIdx.x * 4 + w;          // 0..8191 (2048 blocks)
    #pragma unroll
    for (int it = 0; it < 2; ++it) {
        const int grp = waveId + it * 8192;         // 0..16383
        const int row = grp * 4 + (l >> 4);
        const float4 v = *(const float4*)(x + (size_t)row * NFEAT + d * 4);

        unsigned long long m =
            ((unsigned long long)((int)v.x & 1)) |
            ((unsigned long long)((int)v.y & 1) << 1) |
            ((unsigned long long)((int)v.z & 1) << 2) |
            ((unsigned long long)((int)v.w & 1) << 3);
        m <<= (d * 4);
        m |= __shfl_xor(m, 1); m |= __shfl_xor(m, 2);
        m |= __shfl_xor(m, 4); m |= __shfl_xor(m, 8);
        const float c0 = __shfl(v.z, l | 15);       // x[row][62]
        const float c1 = __shfl(v.w, l | 15);       // x[row][63]

        float fp = v.x * WfL[4 * d] + v.y * WfL[4 * d + 1] +
                   v.z * WfL[4 * d + 2] + v.w * WfL[4 * d + 3];

        float se = 0.f, ssq = 0.f;
        #pragma unroll
        for (int f = 0; f < NDISC; ++f) {
            const int bit = (int)((m >> f) & 1ULL);
            const float e = tblL[(f * 2 + bit) * DIM + d];
            se += e; ssq += e * e;
        }
        {
            const float e62 = bcL[d]      + c0 * WcL[2 * d]            + c1 * WcL[2 * d + 1];
            const float e63 = bcL[16 + d] + c0 * WcL[2 * (16 + d)]     + c1 * WcL[2 * (16 + d) + 1];
            se += e62 + e63; ssq += e62 * e62 + e63 * e63;
        }

        float u = se * se - ssq;
        u  += __shfl_xor(u, 1);  u  += __shfl_xor(u, 2);
        u  += __shfl_xor(u, 4);  u  += __shfl_xor(u, 8);
        fp += __shfl_xor(fp, 1); fp += __shfl_xor(fp, 2);
        fp += __shfl_xor(fp, 4); fp += __shfl_xor(fp, 8);
        if (d == 0) out[(size_t)row * OUTC] = fp + bf0 + 0.5f * u;
    }
}

// ---------------------------------------------------------------- gemm1
// block = 512 thr (8 waves, 2x4), tile 128(M) x 256(N=all H1), BK=64 (4 feats)
// LDS tiles XOR-swizzled: physical 16B slot = logical ^ (row&7).
__global__ __launch_bounds__(512, 4) void gemm1_fused(
        const float* __restrict__ x,
        const float* __restrict__ tbl,
        const float* __restrict__ Wc,
        const float* __restrict__ bc,
        const unsigned short* __restrict__ W1b,
        const float* __restrict__ b1,
        unsigned short* __restrict__ H1b) {
    __shared__ unsigned short ldsA[128 * 64];   // E tile, swizzled slots
    __shared__ unsigned short ldsB[256 * 64];   // W1 tile, swizzled via source
    __shared__ unsigned char  xb[128 * 64];
    __shared__ float contf[128 * 2];
    __shared__ unsigned short tblLb[NDISC * 2 * DIM];   // bf16 emb table
    __shared__ float WcL[64];
    __shared__ float bcL[32];

    const int t  = threadIdx.x;
    const int l  = t & 63;
    const int w  = t >> 6;        // 0..7
    const int wr = w >> 2;        // 0..1  (64-row band)
    const int wc = w & 3;         // 0..3  (64-col band)
    const int m0 = blockIdx.x * 128;

    for (int i = t; i < NDISC * 2 * DIM; i += 512) tblLb[i] = f2bf(tbl[i]);
    if (t < 64) WcL[t] = Wc[t];
    if (t >= 64 && t < 96) bcL[t - 64] = bc[t - 64];

    // stage x tile: thread t -> row t>>2, 16 cols at (t&3)*16, pack bits
    {
        const int row = t >> 2, cbase = (t & 3) * 16;
        const float4* xp = (const float4*)(x + (size_t)(m0 + row) * NFEAT + cbase);
        #pragma unroll
        for (int q = 0; q < 4; ++q) {
            float4 v = xp[q];
            unsigned pk = ((unsigned)(int)v.x) | ((unsigned)(int)v.y << 8) |
                          ((unsigned)(int)v.z << 16) | ((unsigned)(int)v.w << 24);
            *(unsigned*)&xb[row * 64 + cbase + q * 4] = pk;
            if (cbase + q * 4 == 60) {
                contf[row * 2]     = v.z;
                contf[row * 2 + 1] = v.w;
            }
        }
    }
    __syncthreads();

    f32x4 acc[4][4] = {};

    for (int ks = 0; ks < 16; ++ks) {
        const int k0 = ks * 64;
        const int f0 = ks * 4;

        // build A tile: 1024 chunks of 8 bf16; swizzled ds_write slot
        #pragma unroll
        for (int p = 0; p < 2; ++p) {
            const int chunk = p * 512 + t;
            const int row = chunk >> 3;
            const int cc  = chunk & 7;
            const int fl  = cc >> 1;
            const int d0  = (cc & 1) * 8;
            const int f   = f0 + fl;
            bf16x8 pk;
            if (f < NDISC) {
                const int bit = xb[row * 64 + f] & 1;
                pk = *(const bf16x8*)&tblLb[(f * 2 + bit) * DIM + d0];
            } else {
                const float c0v = contf[row * 2], c1v = contf[row * 2 + 1];
                const int j0 = (f - NDISC) * 16 + d0;
                #pragma unroll
                for (int dd = 0; dd < 8; ++dd) {
                    const int j = j0 + dd;
                    pk[dd] = (short)f2bf(bcL[j] + c0v * WcL[2 * j] + c1v * WcL[2 * j + 1]);
                }
            }
            *(bf16x8*)&ldsA[row * 64 + (cc ^ (row & 7)) * 8] = pk;
        }

        // stage B tile (W1): pre-swizzled GLOBAL source, linear LDS dest
        {
            unsigned short* dstbase = &ldsB[0] + w * 512;   // wave-uniform
            #pragma unroll
            for (int p = 0; p < 4; ++p) {
                const int chunk = p * 512 + t;
                const int row = chunk >> 3;
                const int cc  = chunk & 7;
                const int ccs = cc ^ (row & 7);
                async16(W1b + (size_t)row * K1 + k0 + ccs * 8, dstbase + p * 4096);
            }
        }
        __syncthreads();

        #pragma unroll
        for (int sub = 0; sub < 2; ++sub) {
            const int s = sub * 4 + (l >> 4);   // logical 16B slot
            bf16x8 af[4], bfr[4];
            #pragma unroll
            for (int i = 0; i < 4; ++i) {
                const int ra = wr * 64 + i * 16 + (l & 15);
                af[i] = *(const bf16x8*)&ldsA[ra * 64 + (s ^ (ra & 7)) * 8];
            }
            #pragma unroll
            for (int j = 0; j < 4; ++j) {
                const int rb = wc * 64 + j * 16 + (l & 15);
                bfr[j] = *(const bf16x8*)&ldsB[rb * 64 + (s ^ (rb & 7)) * 8];
            }
            #pragma unroll
            for (int i = 0; i < 4; ++i)
                #pragma unroll
                for (int j = 0; j < 4; ++j)
                    acc[i][j] = __builtin_amdgcn_mfma_f32_16x16x32_bf16(af[i], bfr[j], acc[i][j], 0, 0, 0);
        }
        __syncthreads();
    }

    // epilogue: relu(+b1) -> H1 bf16
    #pragma unroll
    for (int i = 0; i < 4; ++i) {
        const int rbase = m0 + wr * 64 + i * 16 + (l >> 4) * 4;
        #pragma unroll
        for (int j = 0; j < 4; ++j) {
            const int col = wc * 64 + j * 16 + (l & 15);
            const float bias = b1[col];
            #pragma unroll
            for (int r = 0; r < 4; ++r) {
                float v = acc[i][j][r] + bias;
                v = v > 0.f ? v : 0.f;
                H1b[(size_t)(rbase + r) * H1N + col] = f2bf(v);
            }
        }
    }
}

// ---------------------------------------------------------------- gemm2
// block = 256 thr (4 waves, 2x2), tile 128x128, BK=128 (2 k-steps), K=256
// Same swizzle: physical 16B slot = logical ^ (row&7), both tiles via source.
__global__ __launch_bounds__(256, 2) void gemm2_k(
        const unsigned short* __restrict__ H1b,
        const unsigned short* __restrict__ W2b,
        const float* __restrict__ b2,
        float* __restrict__ out) {
    __shared__ unsigned short ldsA[128 * 128];
    __shared__ unsigned short ldsB[128 * 128];
    const int t = threadIdx.x, l = t & 63, w = t >> 6;
    const int wr = w >> 1, wc = w & 1;
    const int m0 = blockIdx.x * 128;

    f32x4 acc[4][4] = {};

    for (int ks = 0; ks < 2; ++ks) {
        const int k0 = ks * 128;
        {
            unsigned short* da = &ldsA[0] + w * 512;   // wave-uniform
            unsigned short* db = &ldsB[0] + w * 512;
            #pragma unroll
            for (int p = 0; p < 8; ++p) {
                const int chunk = p * 256 + t;
                const int row = chunk >> 4;
                const int cc  = chunk & 15;
                const int ccs = cc ^ (row & 7);
                async16(H1b + (size_t)(m0 + row) * H1N + k0 + ccs * 8, da + p * 2048);
            }
            #pragma unroll
            for (int p = 0; p < 8; ++p) {
                const int chunk = p * 256 + t;
                const int row = chunk >> 4;
                const int cc  = chunk & 15;
                const int ccs = cc ^ (row & 7);
                async16(W2b + (size_t)row * H1N + k0 + ccs * 8, db + p * 2048);
            }
        }
        __syncthreads();
        #pragma unroll
        for (int sub = 0; sub < 4; ++sub) {
            const int s = sub * 4 + (l >> 4);
            bf16x8 af[4], bfr[4];
            #pragma unroll
            for (int i = 0; i < 4; ++i) {
                const int ra = wr * 64 + i * 16 + (l & 15);
                af[i] = *(const bf16x8*)&ldsA[ra * 128 + (s ^ (ra & 7)) * 8];
            }
            #pragma unroll
            for (int j = 0; j < 4; ++j) {
                const int rb = wc * 64 + j * 16 + (l & 15);
                bfr[j] = *(const bf16x8*)&ldsB[rb * 128 + (s ^ (rb & 7)) * 8];
            }
            #pragma unroll
            for (int i = 0; i < 4; ++i)
                #pragma unroll
                for (int j = 0; j < 4; ++j)
                    acc[i][j] = __builtin_amdgcn_mfma_f32_16x16x32_bf16(af[i], bfr[j], acc[i][j], 0, 0, 0);
        }
        __syncthreads();
    }

    // epilogue: out[:, 1 + n] = relu(acc + b2[n])
    #pragma unroll
    for (int i = 0; i < 4; ++i) {
        const int rbase = m0 + wr * 64 + i * 16 + (l >> 4) * 4;
        #pragma unroll
        for (int j = 0; j < 4; ++j) {
            const int n = wc * 64 + j * 16 + (l & 15);
            const float bias = b2[n];
            #pragma unroll
            for (int r = 0; r < 4; ++r) {
                float v = acc[i][j][r] + bias;
                v = v > 0.f ? v : 0.f;
                out[(size_t)(rbase + r) * OUTC + 1 + n] = v;
            }
        }
    }
}

// ---------------------------------------------------------------- launch
extern "C" void kernel_launch(void* const* d_in, const int* in_sizes, int n_in,
                              void* d_out, int out_size, void* d_ws, size_t ws_size,
                              hipStream_t stream) {
    const float* x   = (const float*)d_in[0];
    const float* tbl = (const float*)d_in[1];
    const float* Wc  = (const float*)d_in[2];
    const float* bc  = (const float*)d_in[3];
    const float* Wf  = (const float*)d_in[4];
    const float* bfp = (const float*)d_in[5];
    const float* W1  = (const float*)d_in[6];
    const float* b1  = (const float*)d_in[7];
    const float* W2  = (const float*)d_in[8];
    const float* b2  = (const float*)d_in[9];
    float* out = (float*)d_out;

    char* ws = (char*)d_ws;
    unsigned short* W1b = (unsigned short*)ws;                  // 512 KiB
    unsigned short* W2b = (unsigned short*)(ws + 524288);       // 64 KiB
    unsigned short* H1b = (unsigned short*)(ws + 589824);       // 32 MiB

    convert_w<<<dim3(H1N * K1 / 256), dim3(256), 0, stream>>>(W1, W2, W1b, W2b);
    fm_kernel<<<dim3(2048), dim3(256), 0, stream>>>(x, tbl, Wc, bc, Wf, bfp, out);
    gemm1_fused<<<dim3(NROWS / 128), dim3(512), 0, stream>>>(x, tbl, Wc, bc, W1b, b1, H1b);
    gemm2_k<<<dim3(NROWS / 128), dim3(256), 0, stream>>>(H1b, W2b, b2, out);
}

// Round 13
// 140.275 us; speedup vs baseline: 1.7623x; 1.0433x over previous
//
#include <hip/hip_runtime.h>
#include <hip/hip_bf16.h>

// DeepFM fused kernels for MI355X (gfx950).
// Pipeline per launch:
//   1. convert_w  : W1,W2 fp32 -> bf16 in ws
//   2. fm_kernel  : out[:,0] = fm_first + fm_second (fp32, lane-local reduction)
//   3. gemm_fused : H1 = relu(E @ W1^T + b1) kept in LDS, then
//                   out[:,1:129] = relu(H1 @ W2^T + b2)  (single kernel,
//                   no H1 round-trip to HBM; saves ~67 MB intermediate traffic)
// R11: merged gemm2 into gemm1 via LDS phase-2 (H1 tile aliases dead phase-1
//      LDS; same 64KB footprint -> occupancy unchanged at 2 blocks/CU).

#define NROWS   65536
#define NFEAT   64
#define NDISC   62
#define DIM     16
#define K1      1024
#define H1N     256
#define H2N     128
#define OUTC    129

using f32x4  = __attribute__((ext_vector_type(4))) float;
using bf16x8 = __attribute__((ext_vector_type(8))) short;

__device__ __forceinline__ unsigned short f2bf(float f) {
    unsigned u = __builtin_bit_cast(unsigned, f);
    u = (u + 0x7FFFu + ((u >> 16) & 1u)) >> 16;   // RNE
    return (unsigned short)u;
}

__device__ __forceinline__ void async16(const void* g, void* l) {
    __builtin_amdgcn_global_load_lds(
        (const __attribute__((address_space(1))) void*)g,
        (__attribute__((address_space(3))) void*)l, 16, 0, 0);
}

// ---------------------------------------------------------------- convert_w
__global__ __launch_bounds__(256) void convert_w(const float* __restrict__ W1,
                                                 const float* __restrict__ W2,
                                                 unsigned short* __restrict__ W1b,
                                                 unsigned short* __restrict__ W2b) {
    int i = blockIdx.x * 256 + threadIdx.x;
    if (i < H1N * K1) W1b[i] = f2bf(W1[i]);
    if (i < H2N * H1N) W2b[i] = f2bf(W2[i]);
}

// ---------------------------------------------------------------- fm_kernel
// wave = 4 rows x 16 dims; reduction over features is lane-local (registers).
__global__ __launch_bounds__(256) void fm_kernel(const float* __restrict__ x,
                                                 const float* __restrict__ tbl,
                                                 const float* __restrict__ Wc,
                                                 const float* __restrict__ bc,
                                                 const float* __restrict__ Wf,
                                                 const float* __restrict__ bfp,
                                                 float* __restrict__ out) {
    __shared__ float tblL[NDISC * 2 * DIM];
    __shared__ float WcL[64];
    __shared__ float bcL[32];
    __shared__ float WfL[64];
    const int t = threadIdx.x, l = t & 63, w = t >> 6;
    const int d = l & 15;
    for (int i = t; i < NDISC * 2 * DIM; i += 256) tblL[i] = tbl[i];
    if (t < 64) WcL[t] = Wc[t];
    else if (t < 96) bcL[t - 64] = bc[t - 64];
    else if (t < 160) WfL[t - 96] = Wf[t - 96];
    __syncthreads();
    const float bf0 = bfp[0];

    const int waveId = blockIdx.x * 4 + w;          // 0..8191 (2048 blocks)
    #pragma unroll
    for (int it = 0; it < 2; ++it) {
        const int grp = waveId + it * 8192;         // 0..16383
        const int row = grp * 4 + (l >> 4);
        const float4 v = *(const float4*)(x + (size_t)row * NFEAT + d * 4);

        unsigned long long m =
            ((unsigned long long)((int)v.x & 1)) |
            ((unsigned long long)((int)v.y & 1) << 1) |
            ((unsigned long long)((int)v.z & 1) << 2) |
            ((unsigned long long)((int)v.w & 1) << 3);
        m <<= (d * 4);
        m |= __shfl_xor(m, 1); m |= __shfl_xor(m, 2);
        m |= __shfl_xor(m, 4); m |= __shfl_xor(m, 8);
        const float c0 = __shfl(v.z, l | 15);       // x[row][62]
        const float c1 = __shfl(v.w, l | 15);       // x[row][63]

        float fp = v.x * WfL[4 * d] + v.y * WfL[4 * d + 1] +
                   v.z * WfL[4 * d + 2] + v.w * WfL[4 * d + 3];

        float se = 0.f, ssq = 0.f;
        #pragma unroll
        for (int f = 0; f < NDISC; ++f) {
            const int bit = (int)((m >> f) & 1ULL);
            const float e = tblL[(f * 2 + bit) * DIM + d];
            se += e; ssq += e * e;
        }
        {
            const float e62 = bcL[d]      + c0 * WcL[2 * d]        + c1 * WcL[2 * d + 1];
            const float e63 = bcL[16 + d] + c0 * WcL[2 * (16 + d)] + c1 * WcL[2 * (16 + d) + 1];
            se += e62 + e63; ssq += e62 * e62 + e63 * e63;
        }

        float u = se * se - ssq;
        u  += __shfl_xor(u, 1);  u  += __shfl_xor(u, 2);
        u  += __shfl_xor(u, 4);  u  += __shfl_xor(u, 8);
        fp += __shfl_xor(fp, 1); fp += __shfl_xor(fp, 2);
        fp += __shfl_xor(fp, 4); fp += __shfl_xor(fp, 8);
        if (d == 0) out[(size_t)row * OUTC] = fp + bf0 + 0.5f * u;
    }
}

// ---------------------------------------------------------------- gemm_fused
// block = 512 thr (8 waves, 2x4), tile 128(M) x 256(N=all H1), BK=64.
// Phase 1: H1 tile via MFMA (LDS XOR-swizzled, slot ^= row&7).
// Phase 2: H1 tile -> LDS (aliases dead phase-1 LDS), out = relu(H1 @ W2^T + b2).
__global__ __launch_bounds__(512, 4) void gemm_fused(
        const float* __restrict__ x,
        const float* __restrict__ tbl,
        const float* __restrict__ Wc,
        const float* __restrict__ bc,
        const unsigned short* __restrict__ W1b,
        const float* __restrict__ b1,
        const unsigned short* __restrict__ W2b,
        const float* __restrict__ b2,
        float* __restrict__ out) {
    // flat LDS: phase-1 regions die before phase-2's H1t overwrites them
    __shared__ __align__(16) char smem[65536];
    unsigned short* ldsA  = (unsigned short*)(smem);           // [128*64]   16 KB
    unsigned short* ldsB  = (unsigned short*)(smem + 16384);   // [256*64]   32 KB
    unsigned char*  xb    = (unsigned char*)(smem + 49152);    // [128*64]    8 KB
    float*          contf = (float*)(smem + 57344);            // [256]       1 KB
    unsigned short* tblLb = (unsigned short*)(smem + 58368);   // [1984]    3.9 KB
    float*          WcL   = (float*)(smem + 62336);            // [64]
    float*          bcL   = (float*)(smem + 62592);            // [32]
    unsigned short* H1t   = (unsigned short*)(smem);           // [128*256]  64 KB (phase 2)

    const int t  = threadIdx.x;
    const int l  = t & 63;
    const int w  = t >> 6;        // 0..7
    const int wr = w >> 2;        // 0..1  (64-row band)
    const int wc = w & 3;         // 0..3  (64-col band; 32-col band in phase 2)
    const int m0 = blockIdx.x * 128;

    for (int i = t; i < NDISC * 2 * DIM; i += 512) tblLb[i] = f2bf(tbl[i]);
    if (t < 64) WcL[t] = Wc[t];
    if (t >= 64 && t < 96) bcL[t - 64] = bc[t - 64];

    // stage x tile: thread t -> row t>>2, 16 cols at (t&3)*16, pack bits
    {
        const int row = t >> 2, cbase = (t & 3) * 16;
        const float4* xp = (const float4*)(x + (size_t)(m0 + row) * NFEAT + cbase);
        #pragma unroll
        for (int q = 0; q < 4; ++q) {
            float4 v = xp[q];
            unsigned pk = ((unsigned)(int)v.x) | ((unsigned)(int)v.y << 8) |
                          ((unsigned)(int)v.z << 16) | ((unsigned)(int)v.w << 24);
            *(unsigned*)&xb[row * 64 + cbase + q * 4] = pk;
            if (cbase + q * 4 == 60) {
                contf[row * 2]     = v.z;
                contf[row * 2 + 1] = v.w;
            }
        }
    }
    __syncthreads();

    f32x4 acc[4][4] = {};

    for (int ks = 0; ks < 16; ++ks) {
        const int k0 = ks * 64;
        const int f0 = ks * 4;

        // build A tile: 1024 chunks of 8 bf16; swizzled ds_write slot
        #pragma unroll
        for (int p = 0; p < 2; ++p) {
            const int chunk = p * 512 + t;
            const int row = chunk >> 3;
            const int cc  = chunk & 7;
            const int fl  = cc >> 1;
            const int d0  = (cc & 1) * 8;
            const int f   = f0 + fl;
            bf16x8 pk;
            if (f < NDISC) {
                const int bit = xb[row * 64 + f] & 1;
                pk = *(const bf16x8*)&tblLb[(f * 2 + bit) * DIM + d0];
            } else {
                const float c0v = contf[row * 2], c1v = contf[row * 2 + 1];
                const int j0 = (f - NDISC) * 16 + d0;
                #pragma unroll
                for (int dd = 0; dd < 8; ++dd) {
                    const int j = j0 + dd;
                    pk[dd] = (short)f2bf(bcL[j] + c0v * WcL[2 * j] + c1v * WcL[2 * j + 1]);
                }
            }
            *(bf16x8*)&ldsA[row * 64 + (cc ^ (row & 7)) * 8] = pk;
        }

        // stage B tile (W1): pre-swizzled GLOBAL source, linear LDS dest
        {
            unsigned short* dstbase = ldsB + w * 512;   // wave-uniform
            #pragma unroll
            for (int p = 0; p < 4; ++p) {
                const int chunk = p * 512 + t;
                const int row = chunk >> 3;
                const int cc  = chunk & 7;
                const int ccs = cc ^ (row & 7);
                async16(W1b + (size_t)row * K1 + k0 + ccs * 8, dstbase + p * 4096);
            }
        }
        __syncthreads();

        #pragma unroll
        for (int sub = 0; sub < 2; ++sub) {
            const int s = sub * 4 + (l >> 4);   // logical 16B slot
            bf16x8 af[4], bfr[4];
            #pragma unroll
            for (int i = 0; i < 4; ++i) {
                const int ra = wr * 64 + i * 16 + (l & 15);
                af[i] = *(const bf16x8*)&ldsA[ra * 64 + (s ^ (ra & 7)) * 8];
            }
            #pragma unroll
            for (int j = 0; j < 4; ++j) {
                const int rb = wc * 64 + j * 16 + (l & 15);
                bfr[j] = *(const bf16x8*)&ldsB[rb * 64 + (s ^ (rb & 7)) * 8];
            }
            #pragma unroll
            for (int i = 0; i < 4; ++i)
                #pragma unroll
                for (int j = 0; j < 4; ++j)
                    acc[i][j] = __builtin_amdgcn_mfma_f32_16x16x32_bf16(af[i], bfr[j], acc[i][j], 0, 0, 0);
        }
        __syncthreads();
    }

    // phase transition: relu(+b1) -> H1 tile in LDS (swizzled: slot ^= row&7)
    #pragma unroll
    for (int i = 0; i < 4; ++i) {
        const int rloc0 = wr * 64 + i * 16 + (l >> 4) * 4;
        #pragma unroll
        for (int j = 0; j < 4; ++j) {
            const int col  = wc * 64 + j * 16 + (l & 15);
            const int slot = col >> 3, cin = col & 7;
            const float bias = b1[col];
            #pragma unroll
            for (int r = 0; r < 4; ++r) {
                const int row = rloc0 + r;
                float v = acc[i][j][r] + bias;
                v = v > 0.f ? v : 0.f;
                H1t[row * 256 + (slot ^ (row & 7)) * 8 + cin] = f2bf(v);
            }
        }
    }
    __syncthreads();

    // phase 2: out[128 x 128] = relu(H1t @ W2^T + b2); wave = 64 rows x 32 cols
    f32x4 acc2[4][2] = {};
    #pragma unroll
    for (int kk = 0; kk < 8; ++kk) {
        bf16x8 bfr2[2];
        #pragma unroll
        for (int j2 = 0; j2 < 2; ++j2) {
            const int nrow = wc * 32 + j2 * 16 + (l & 15);
            bfr2[j2] = *(const bf16x8*)(W2b + (size_t)nrow * H1N + kk * 32 + (l >> 4) * 8);
        }
        const int slot = kk * 4 + (l >> 4);
        #pragma unroll
        for (int i2 = 0; i2 < 4; ++i2) {
            const int ra = wr * 64 + i2 * 16 + (l & 15);
            const bf16x8 af2 = *(const bf16x8*)&H1t[ra * 256 + (slot ^ (ra & 7)) * 8];
            #pragma unroll
            for (int j2 = 0; j2 < 2; ++j2)
                acc2[i2][j2] = __builtin_amdgcn_mfma_f32_16x16x32_bf16(af2, bfr2[j2], acc2[i2][j2], 0, 0, 0);
        }
    }

    // epilogue: out[:, 1 + n] = relu(acc2 + b2[n])
    #pragma unroll
    for (int i2 = 0; i2 < 4; ++i2) {
        const int rbase = m0 + wr * 64 + i2 * 16 + (l >> 4) * 4;
        #pragma unroll
        for (int j2 = 0; j2 < 2; ++j2) {
            const int n = wc * 32 + j2 * 16 + (l & 15);
            const float bias = b2[n];
            #pragma unroll
            for (int r = 0; r < 4; ++r) {
                float v = acc2[i2][j2][r] + bias;
                v = v > 0.f ? v : 0.f;
                out[(size_t)(rbase + r) * OUTC + 1 + n] = v;
            }
        }
    }
}

// ---------------------------------------------------------------- launch
extern "C" void kernel_launch(void* const* d_in, const int* in_sizes, int n_in,
                              void* d_out, int out_size, void* d_ws, size_t ws_size,
                              hipStream_t stream) {
    const float* x   = (const float*)d_in[0];
    const float* tbl = (const float*)d_in[1];
    const float* Wc  = (const float*)d_in[2];
    const float* bc  = (const float*)d_in[3];
    const float* Wf  = (const float*)d_in[4];
    const float* bfp = (const float*)d_in[5];
    const float* W1  = (const float*)d_in[6];
    const float* b1  = (const float*)d_in[7];
    const float* W2  = (const float*)d_in[8];
    const float* b2  = (const float*)d_in[9];
    float* out = (float*)d_out;

    char* ws = (char*)d_ws;
    unsigned short* W1b = (unsigned short*)ws;                  // 512 KiB
    unsigned short* W2b = (unsigned short*)(ws + 524288);       // 64 KiB

    convert_w<<<dim3(H1N * K1 / 256), dim3(256), 0, stream>>>(W1, W2, W1b, W2b);
    fm_kernel<<<dim3(2048), dim3(256), 0, stream>>>(x, tbl, Wc, bc, Wf, bfp, out);
    gemm_fused<<<dim3(NROWS / 128), dim3(512), 0, stream>>>(x, tbl, Wc, bc, W1b, b1,
                                                            W2b, b2, out);
}

// Round 15
// 118.574 us; speedup vs baseline: 2.0848x; 1.1830x over previous
//
#include <hip/hip_runtime.h>
#include <hip/hip_bf16.h>

// DeepFM fused kernels for MI355X (gfx950).
// R13: GEMM1 K-collapse 1024 -> 64. Since disc e_f = t0 + bit*(t1-t0) and bits
// come straight from x (x in {0,1}), H1 = relu(xb16 @ D'^T + biasTot) with
//   D'[c][f<62] = sum_d (t1-t0)[d] * W1[c][16f+d]   (precomputed, fp32->bf16)
//   D'[c][62/63] = P0/P1 (cont affine),  biasTot = b1 + base + bc-part.
// A-tile = bf16(x tile) exactly. Phase 2 (H1 @ W2^T) unchanged from R12 (validated).
// Pipeline: convert_w2 (W2->bf16) ; prep (D', biasTot) ; fm_kernel ; gemm_fused.

#define NROWS   65536
#define NFEAT   64
#define NDISC   62
#define DIM     16
#define K1      1024
#define H1N     256
#define H2N     128
#define OUTC    129

using f32x4  = __attribute__((ext_vector_type(4))) float;
using bf16x8 = __attribute__((ext_vector_type(8))) short;

__device__ __forceinline__ unsigned short f2bf(float f) {
    unsigned u = __builtin_bit_cast(unsigned, f);
    u = (u + 0x7FFFu + ((u >> 16) & 1u)) >> 16;   // RNE
    return (unsigned short)u;
}

__device__ __forceinline__ void async16(const void* g, void* l) {
    __builtin_amdgcn_global_load_lds(
        (const __attribute__((address_space(1))) void*)g,
        (__attribute__((address_space(3))) void*)l, 16, 0, 0);
}

// ---------------------------------------------------------------- convert_w2
__global__ __launch_bounds__(256) void convert_w2(const float* __restrict__ W2,
                                                  unsigned short* __restrict__ W2b) {
    int i = blockIdx.x * 256 + threadIdx.x;
    if (i < H2N * H1N) W2b[i] = f2bf(W2[i]);
}

// ---------------------------------------------------------------- prep
// thread (c,k): D'[c][k] and bias partial; one wave handles one c (k=0..63).
__global__ __launch_bounds__(256) void prep(const float* __restrict__ tbl,
                                            const float* __restrict__ Wc,
                                            const float* __restrict__ bc,
                                            const float* __restrict__ W1,
                                            const float* __restrict__ b1,
                                            unsigned short* __restrict__ Dp,
                                            float* __restrict__ biasTot) {
    const int g = blockIdx.x * 256 + threadIdx.x;   // 0..16383
    const int c = g >> 6, k = g & 63;
    const float* w1r = W1 + (size_t)c * K1;
    float delta = 0.f, part = 0.f;
    if (k < NDISC) {
        #pragma unroll
        for (int d = 0; d < 16; ++d) {
            const float t0 = tbl[(k * 2) * 16 + d];
            const float t1 = tbl[(k * 2 + 1) * 16 + d];
            const float w  = w1r[k * 16 + d];
            delta += (t1 - t0) * w;
            part  += t0 * w;
        }
    } else if (k == 62) {
        #pragma unroll
        for (int j = 0; j < 32; ++j) delta += Wc[j * 2] * w1r[992 + j];
        #pragma unroll
        for (int j = 0; j < 16; ++j) part += bc[j] * w1r[992 + j];
    } else {
        #pragma unroll
        for (int j = 0; j < 32; ++j) delta += Wc[j * 2 + 1] * w1r[992 + j];
        #pragma unroll
        for (int j = 0; j < 16; ++j) part += bc[16 + j] * w1r[1008 + j];
    }
    Dp[(size_t)c * 64 + k] = f2bf(delta);
    // wave-reduce bias partials (one c per wave, 64-lane aligned)
    part += __shfl_xor(part, 1);  part += __shfl_xor(part, 2);
    part += __shfl_xor(part, 4);  part += __shfl_xor(part, 8);
    part += __shfl_xor(part, 16); part += __shfl_xor(part, 32);
    if (k == 0) biasTot[c] = part + b1[c];
}

// ---------------------------------------------------------------- fm_kernel
// wave = 4 rows x 16 dims; reduction over features is lane-local (registers).
__global__ __launch_bounds__(256) void fm_kernel(const float* __restrict__ x,
                                                 const float* __restrict__ tbl,
                                                 const float* __restrict__ Wc,
                                                 const float* __restrict__ bc,
                                                 const float* __restrict__ Wf,
                                                 const float* __restrict__ bfp,
                                                 float* __restrict__ out) {
    __shared__ float tblL[NDISC * 2 * DIM];
    __shared__ float WcL[64];
    __shared__ float bcL[32];
    __shared__ float WfL[64];
    const int t = threadIdx.x, l = t & 63, w = t >> 6;
    const int d = l & 15;
    for (int i = t; i < NDISC * 2 * DIM; i += 256) tblL[i] = tbl[i];
    if (t < 64) WcL[t] = Wc[t];
    else if (t < 96) bcL[t - 64] = bc[t - 64];
    else if (t < 160) WfL[t - 96] = Wf[t - 96];
    __syncthreads();
    const float bf0 = bfp[0];

    const int waveId = blockIdx.x * 4 + w;          // 0..8191 (2048 blocks)
    #pragma unroll
    for (int it = 0; it < 2; ++it) {
        const int grp = waveId + it * 8192;         // 0..16383
        const int row = grp * 4 + (l >> 4);
        const float4 v = *(const float4*)(x + (size_t)row * NFEAT + d * 4);

        unsigned long long m =
            ((unsigned long long)((int)v.x & 1)) |
            ((unsigned long long)((int)v.y & 1) << 1) |
            ((unsigned long long)((int)v.z & 1) << 2) |
            ((unsigned long long)((int)v.w & 1) << 3);
        m <<= (d * 4);
        m |= __shfl_xor(m, 1); m |= __shfl_xor(m, 2);
        m |= __shfl_xor(m, 4); m |= __shfl_xor(m, 8);
        const float c0 = __shfl(v.z, l | 15);       // x[row][62]
        const float c1 = __shfl(v.w, l | 15);       // x[row][63]

        float fp = v.x * WfL[4 * d] + v.y * WfL[4 * d + 1] +
                   v.z * WfL[4 * d + 2] + v.w * WfL[4 * d + 3];

        float se = 0.f, ssq = 0.f;
        #pragma unroll
        for (int f = 0; f < NDISC; ++f) {
            const int bit = (int)((m >> f) & 1ULL);
            const float e = tblL[(f * 2 + bit) * DIM + d];
            se += e; ssq += e * e;
        }
        {
            const float e62 = bcL[d]      + c0 * WcL[2 * d]        + c1 * WcL[2 * d + 1];
            const float e63 = bcL[16 + d] + c0 * WcL[2 * (16 + d)] + c1 * WcL[2 * (16 + d) + 1];
            se += e62 + e63; ssq += e62 * e62 + e63 * e63;
        }

        float u = se * se - ssq;
        u  += __shfl_xor(u, 1);  u  += __shfl_xor(u, 2);
        u  += __shfl_xor(u, 4);  u  += __shfl_xor(u, 8);
        fp += __shfl_xor(fp, 1); fp += __shfl_xor(fp, 2);
        fp += __shfl_xor(fp, 4); fp += __shfl_xor(fp, 8);
        if (d == 0) out[(size_t)row * OUTC] = fp + bf0 + 0.5f * u;
    }
}

// ---------------------------------------------------------------- gemm_fused
// block = 512 thr (8 waves, 2x4), tile 128(M) x 256(N), K=64 single step.
// Phase 1: H1 = relu(xb16 @ D'^T + biasTot) via MFMA (swizzle slot ^= row&7).
// Phase 2: H1 tile in LDS (aliases phase-1), out = relu(H1 @ W2^T + b2).
__global__ __launch_bounds__(512, 4) void gemm_fused(
        const float* __restrict__ x,
        const unsigned short* __restrict__ Dp,
        const float* __restrict__ biasTot,
        const unsigned short* __restrict__ W2b,
        const float* __restrict__ b2,
        float* __restrict__ out) {
    __shared__ __align__(16) char smem[65536];
    unsigned short* ldsA = (unsigned short*)(smem);            // [128*64] 16 KB
    unsigned short* ldsB = (unsigned short*)(smem + 16384);    // [256*64] 32 KB
    unsigned short* H1t  = (unsigned short*)(smem);            // [128*256] 64 KB (ph2)

    const int t  = threadIdx.x;
    const int l  = t & 63;
    const int w  = t >> 6;        // 0..7
    const int wr = w >> 2;        // 0..1
    const int wc = w & 3;         // 0..3 (32-col band in phase 2)
    const int m0 = blockIdx.x * 128;

    // stage B (D'): 2048 x 16B chunks, pre-swizzled source, linear dest
    {
        unsigned short* dstbase = ldsB + w * 512;   // wave-uniform
        #pragma unroll
        for (int p = 0; p < 4; ++p) {
            const int chunk = p * 512 + t;
            const int row = chunk >> 3;             // c 0..255
            const int cc  = chunk & 7;
            const int ccs = cc ^ (row & 7);
            async16(Dp + (size_t)row * 64 + ccs * 8, dstbase + p * 4096);
        }
    }

    // stage A: x tile -> bf16, swizzled write. thread: row=t>>2, 16 cols.
    {
        const int row = t >> 2, q3 = t & 3;
        const float4* xp = (const float4*)(x + (size_t)(m0 + row) * NFEAT + q3 * 16);
        #pragma unroll
        for (int qq = 0; qq < 2; ++qq) {
            float4 v0 = xp[qq * 2], v1 = xp[qq * 2 + 1];
            bf16x8 pk;
            pk[0] = (short)f2bf(v0.x); pk[1] = (short)f2bf(v0.y);
            pk[2] = (short)f2bf(v0.z); pk[3] = (short)f2bf(v0.w);
            pk[4] = (short)f2bf(v1.x); pk[5] = (short)f2bf(v1.y);
            pk[6] = (short)f2bf(v1.z); pk[7] = (short)f2bf(v1.w);
            const int cc = q3 * 2 + qq;
            *(bf16x8*)&ldsA[row * 64 + (cc ^ (row & 7)) * 8] = pk;
        }
    }
    __syncthreads();

    // phase 1 MFMA: K=64 -> 2 sub-steps of K=32
    f32x4 acc[4][4] = {};
    #pragma unroll
    for (int sub = 0; sub < 2; ++sub) {
        const int s = sub * 4 + (l >> 4);   // logical 16B slot
        bf16x8 af[4], bfr[4];
        #pragma unroll
        for (int i = 0; i < 4; ++i) {
            const int ra = wr * 64 + i * 16 + (l & 15);
            af[i] = *(const bf16x8*)&ldsA[ra * 64 + (s ^ (ra & 7)) * 8];
        }
        #pragma unroll
        for (int j = 0; j < 4; ++j) {
            const int rb = wc * 64 + j * 16 + (l & 15);
            bfr[j] = *(const bf16x8*)&ldsB[rb * 64 + (s ^ (rb & 7)) * 8];
        }
        #pragma unroll
        for (int i = 0; i < 4; ++i)
            #pragma unroll
            for (int j = 0; j < 4; ++j)
                acc[i][j] = __builtin_amdgcn_mfma_f32_16x16x32_bf16(af[i], bfr[j], acc[i][j], 0, 0, 0);
    }
    __syncthreads();

    // phase transition: relu(+biasTot) -> H1 tile in LDS (slot ^= row&7)
    #pragma unroll
    for (int i = 0; i < 4; ++i) {
        const int rloc0 = wr * 64 + i * 16 + (l >> 4) * 4;
        #pragma unroll
        for (int j = 0; j < 4; ++j) {
            const int col  = wc * 64 + j * 16 + (l & 15);
            const int slot = col >> 3, cin = col & 7;
            const float bias = biasTot[col];
            #pragma unroll
            for (int r = 0; r < 4; ++r) {
                const int row = rloc0 + r;
                float v = acc[i][j][r] + bias;
                v = v > 0.f ? v : 0.f;
                H1t[row * 256 + (slot ^ (row & 7)) * 8 + cin] = f2bf(v);
            }
        }
    }
    __syncthreads();

    // phase 2: out[128 x 128] = relu(H1t @ W2^T + b2); wave = 64 rows x 32 cols
    f32x4 acc2[4][2] = {};
    #pragma unroll
    for (int kk = 0; kk < 8; ++kk) {
        bf16x8 bfr2[2];
        #pragma unroll
        for (int j2 = 0; j2 < 2; ++j2) {
            const int nrow = wc * 32 + j2 * 16 + (l & 15);
            bfr2[j2] = *(const bf16x8*)(W2b + (size_t)nrow * H1N + kk * 32 + (l >> 4) * 8);
        }
        const int slot = kk * 4 + (l >> 4);
        #pragma unroll
        for (int i2 = 0; i2 < 4; ++i2) {
            const int ra = wr * 64 + i2 * 16 + (l & 15);
            const bf16x8 af2 = *(const bf16x8*)&H1t[ra * 256 + (slot ^ (ra & 7)) * 8];
            #pragma unroll
            for (int j2 = 0; j2 < 2; ++j2)
                acc2[i2][j2] = __builtin_amdgcn_mfma_f32_16x16x32_bf16(af2, bfr2[j2], acc2[i2][j2], 0, 0, 0);
        }
    }

    // epilogue: out[:, 1 + n] = relu(acc2 + b2[n])
    #pragma unroll
    for (int i2 = 0; i2 < 4; ++i2) {
        const int rbase = m0 + wr * 64 + i2 * 16 + (l >> 4) * 4;
        #pragma unroll
        for (int j2 = 0; j2 < 2; ++j2) {
            const int n = wc * 32 + j2 * 16 + (l & 15);
            const float bias = b2[n];
            #pragma unroll
            for (int r = 0; r < 4; ++r) {
                float v = acc2[i2][j2][r] + bias;
                v = v > 0.f ? v : 0.f;
                out[(size_t)(rbase + r) * OUTC + 1 + n] = v;
            }
        }
    }
}

// ---------------------------------------------------------------- launch
extern "C" void kernel_launch(void* const* d_in, const int* in_sizes, int n_in,
                              void* d_out, int out_size, void* d_ws, size_t ws_size,
                              hipStream_t stream) {
    const float* x   = (const float*)d_in[0];
    const float* tbl = (const float*)d_in[1];
    const float* Wc  = (const float*)d_in[2];
    const float* bc  = (const float*)d_in[3];
    const float* Wf  = (const float*)d_in[4];
    const float* bfp = (const float*)d_in[5];
    const float* W1  = (const float*)d_in[6];
    const float* b1  = (const float*)d_in[7];
    const float* W2  = (const float*)d_in[8];
    const float* b2  = (const float*)d_in[9];
    float* out = (float*)d_out;

    char* ws = (char*)d_ws;
    unsigned short* W2b     = (unsigned short*)ws;               // 64 KiB
    unsigned short* Dp      = (unsigned short*)(ws + 65536);     // 32 KiB
    float*          biasTot = (float*)(ws + 98304);              // 1 KiB

    convert_w2<<<dim3(H2N * H1N / 256), dim3(256), 0, stream>>>(W2, W2b);
    prep<<<dim3(64), dim3(256), 0, stream>>>(tbl, Wc, bc, W1, b1, Dp, biasTot);
    fm_kernel<<<dim3(2048), dim3(256), 0, stream>>>(x, tbl, Wc, bc, Wf, bfp, out);
    gemm_fused<<<dim3(NROWS / 128), dim3(512), 0, stream>>>(x, Dp, biasTot, W2b, b2, out);
}